// Round 1
// baseline (13431.606 us; speedup 1.0000x reference)
//
#include <hip/hip_runtime.h>
#include <math.h>

typedef float2 cplx;

#define PI_F 3.14159265358979323846f
#define SQC  0.8944271909999159f   // sqrt(0.8) = sqrt(2^6 * 3!^2 / (4 * 6!))

#define GS_FOR(i, n) for (int i = blockIdx.x * blockDim.x + threadIdx.x; i < (n); i += gridDim.x * blockDim.x)

// ---------------- device helpers ----------------
__device__ __forceinline__ float ufreq(int i, int n) {
  return (float)((i < (n >> 1)) ? i : i - n) * (2.0f / (float)n);
}
// filters evaluated at UNSHIFTED frequency coords (ifftshift folded into index math)
__device__ __forceinline__ void grid_lr_ang(int i, int j, int n, float* lr, float* ang) {
  float fy = ufreq(i, n), fx = ufreq(j, n);
  float r = sqrtf(fx * fx + fy * fy);
  if (i == 0 && j == 0) r = 1.0f / (float)n;  // DC: r==0 -> 1/max(h,w)
  *lr = log2f(r);
  *ang = atan2f(fy, fx);
}
__device__ __forceinline__ float rc_hi_f(float lr, float lo, float hi) {
  float t = (lr - lo) / (hi - lo);
  t = fminf(fmaxf(t, 0.0f), 1.0f);
  return sqrtf(0.5f * (1.0f - cosf(PI_F * t)));
}
__device__ __forceinline__ float rc_lo_f(float lr, float lo, float hi) {
  float t = (lr - lo) / (hi - lo);
  t = fminf(fmaxf(t, 0.0f), 1.0f);
  return sqrtf(0.5f * (1.0f + cosf(PI_F * t)));
}
__device__ __forceinline__ float wrap_d(float ang, int b) {
  float d = ang - PI_F * (float)b * 0.25f + PI_F;
  d = d - floorf(d * (0.5f / PI_F)) * (2.0f * PI_F);
  return d - PI_F;
}
__device__ __forceinline__ float amask_c(float ang, int b) {   // complex-pyramid mask
  float d = wrap_d(ang, b);
  float c = cosf(d);
  float m = 2.0f * SQC * c * c * c;
  return (fabsf(d) < 0.5f * PI_F) ? m : 0.0f;
}
__device__ __forceinline__ float amask_r(float ang, int b) {   // real recon mask
  float d = wrap_d(ang, b);
  float c = cosf(d);
  return SQC * c * c * c;
}

__device__ __forceinline__ double wred_d(double v) {
#pragma unroll
  for (int o = 32; o > 0; o >>= 1) v += __shfl_down(v, o);
  return v;
}
__device__ __forceinline__ void atom_add_wave(double* slot, double v) {
  v = wred_d(v);
  if ((threadIdx.x & 63) == 0) atomicAdd(slot, v);
}
__device__ __forceinline__ void atomicMinF(float* a, float v) {
  if (v >= 0.0f) atomicMin((int*)a, __float_as_int(v));
  else atomicMax((unsigned int*)a, __float_as_uint(v));
}
__device__ __forceinline__ void atomicMaxF(float* a, float v) {
  if (v >= 0.0f) atomicMax((int*)a, __float_as_int(v));
  else atomicMin((unsigned int*)a, __float_as_uint(v));
}

// ---------------- FFT: one block per row, radix-2 DIT in LDS ----------------
template<int LOGN, bool INV>
__global__ __launch_bounds__(256) void fft_rows_k(cplx* __restrict__ d) {
  constexpr int N = 1 << LOGN;
  __shared__ cplx sh[N];
  __shared__ cplx tw[N / 2];
  const int tid = threadIdx.x;
  const int T = blockDim.x;
  cplx* rp = d + (size_t)blockIdx.x * N;
  for (int k = tid; k < N / 2; k += T) {
    float a = (INV ? 2.0f : -2.0f) * PI_F * (float)k / (float)N;
    float s, c;
    sincosf(a, &s, &c);
    tw[k] = make_float2(c, s);
  }
  for (int i = tid; i < N; i += T) {
    unsigned r = __brev((unsigned)i) >> (32 - LOGN);
    sh[r] = rp[i];
  }
  __syncthreads();
  for (int len = 2; len <= N; len <<= 1) {
    const int half = len >> 1;
    const int tstep = N / len;
    for (int j = tid; j < N / 2; j += T) {
      int pos = j & (half - 1);
      int base = (j - pos) << 1;
      cplx w = tw[pos * tstep];
      cplx a = sh[base + pos];
      cplx b = sh[base + pos + half];
      float tx = b.x * w.x - b.y * w.y;
      float ty = b.x * w.y + b.y * w.x;
      sh[base + pos] = make_float2(a.x + tx, a.y + ty);
      sh[base + pos + half] = make_float2(a.x - tx, a.y - ty);
    }
    __syncthreads();
  }
  const float sc = INV ? (1.0f / (float)N) : 1.0f;
  for (int i = tid; i < N; i += T) {
    cplx v = sh[i];
    rp[i] = make_float2(v.x * sc, v.y * sc);
  }
}

__global__ void transpose_k(cplx* __restrict__ out, const cplx* __restrict__ in, int N) {
  __shared__ cplx tile[32][33];
  size_t po = (size_t)blockIdx.z * N * N;
  int bx = blockIdx.x * 32, by = blockIdx.y * 32;
  int x = bx + threadIdx.x;
  for (int dy = threadIdx.y; dy < 32; dy += 8)
    tile[dy][threadIdx.x] = in[po + (size_t)(by + dy) * N + x];
  __syncthreads();
  int xo = by + threadIdx.x;
  for (int dy = threadIdx.y; dy < 32; dy += 8)
    out[po + (size_t)(bx + dy) * N + xo] = tile[threadIdx.x][dy];
}

// ---------------- pointwise / gather kernels ----------------
__global__ void r2c_k(cplx* out, const float* in, int n) {
  GS_FOR(i, n) out[i] = make_float2(in[i], 0.0f);
}
__global__ void hp_lo_split_k(cplx* hp, cplx* lod, const cplx* spec, int logN) {
  int N = 1 << logN, n = N * N;
  GS_FOR(idx, n) {
    int i = idx >> logN, j = idx & (N - 1);
    float lr, ang;
    grid_lr_ang(i, j, N, &lr, &ang);
    float h0 = rc_hi_f(lr, -1.0f, 0.0f);
    float l0 = rc_lo_f(lr, -1.0f, 0.0f);
    cplx z = spec[idx];
    hp[idx]  = make_float2(z.x * h0, z.y * h0);
    lod[idx] = make_float2(z.x * l0, z.y * l0);
  }
}
// out[p] = cph * lod * him * amask_c(b0+p);  cph = (-i)^3 = +i
__global__ void band_spec_k(cplx* out, const cplx* lod, int logN, int b0, int P) {
  int N = 1 << logN, n = N * N;
  GS_FOR(idx, n) {
    int i = idx >> logN, j = idx & (N - 1);
    float lr, ang;
    grid_lr_ang(i, j, N, &lr, &ang);
    float him = rc_hi_f(lr, -2.0f, -1.0f);
    cplx z = lod[idx];
    for (int p = 0; p < P; ++p) {
      float m = him * amask_c(ang, b0 + p);
      out[p * n + idx] = make_float2(-z.y * m, z.x * m);  // i*(x+iy)*m
    }
  }
}
__global__ void extract_band_k(float* realc, float* mag, cplx* coeff, const cplx* src,
                               int logPer, int P, double* acc0) {
  int n = (1 << logPer) * P;
  double s0 = 0, s1 = 0, s2 = 0, s3 = 0;
  GS_FOR(idx, n) {
    cplx z = src[idx];
    float m = sqrtf(z.x * z.x + z.y * z.y);
    realc[idx] = z.x;
    mag[idx] = m;
    if (coeff) coeff[idx] = z;
    int p = idx >> logPer;
    if (p == 0) s0 += m; else if (p == 1) s1 += m; else if (p == 2) s2 += m; else s3 += m;
  }
  atom_add_wave(acc0 + 0, s0);
  if (P > 1) {
    atom_add_wave(acc0 + 1, s1);
    atom_add_wave(acc0 + 2, s2);
    atom_add_wave(acc0 + 3, s3);
  }
}
__global__ void center_k(float* buf, int logPer, int P, const double* acc0) {
  int nPer = 1 << logPer, n = nPer * P;
  double inv = 1.0 / (double)nPer;
  GS_FOR(idx, n) buf[idx] -= (float)(acc0[idx >> logPer] * inv);
}
// crop center-half of (shifted) spectrum == low-freq gather in unshifted coords, * rc_lo at child grid
__global__ void lod_down_k(cplx* child, const cplx* par, int logNc) {
  int Nc = 1 << logNc, n = Nc * Nc, Np = Nc << 1;
  GS_FOR(idx, n) {
    int i = idx >> logNc, j = idx & (Nc - 1);
    int pi = (i < (Nc >> 1)) ? i : i + Nc;
    int pj = (j < (Nc >> 1)) ? j : j + Nc;
    float lr, ang;
    grid_lr_ang(i, j, Nc, &lr, &ang);
    float l0 = rc_lo_f(lr, -1.0f, 0.0f);
    cplx z = par[pi * Np + pj];
    child[idx] = make_float2(z.x * l0, z.y * l0);
  }
}
__global__ void extract_real_k(float* out, const cplx* src, int n, double* sumAcc) {
  double s = 0;
  GS_FOR(i, n) { float v = src[i].x; out[i] = v; s += v; }
  if (sumAcc) atom_add_wave(sumAcc, s);
}
__global__ void center_abs_k(float* buf, int n, const double* sumAcc, double* absAcc) {
  float mu = (float)(*sumAcc / (double)n);
  double s = 0;
  GS_FOR(i, n) { float v = buf[i] - mu; buf[i] = v; s += fabsf(v); }
  atom_add_wave(absAcc, s);
}
__global__ void rhp_extract_k(float* out, const cplx* src, int n, double* accAbs, double* accSq) {
  double sa = 0, sq = 0;
  GS_FOR(i, n) {
    float v = src[i].x;
    out[i] = v;
    sa += fabsf(v);
    sq += (double)v * (double)v;
  }
  atom_add_wave(accAbs, sa);
  atom_add_wave(accSq, sq);
}
__global__ void mul_lo0_k(cplx* a, int logN) {
  int N = 1 << logN, n = N * N;
  GS_FOR(idx, n) {
    int i = idx >> logN, j = idx & (N - 1);
    float lr, ang;
    grid_lr_ang(i, j, N, &lr, &ang);
    float l0 = rc_lo_f(lr, -1.0f, 0.0f);
    a[idx].x *= l0;
    a[idx].y *= l0;
  }
}
__global__ void sqmag_k(cplx* a, int n) {
  GS_FOR(i, n) { cplx z = a[i]; a[i] = make_float2(z.x * z.x + z.y * z.y, 0.0f); }
}
// zero-pad embed (expand): big unshifted freq f == child's for |f| < child nyquist band
__global__ void embed_k(cplx* big, const cplx* sml, int logNb, int P) {
  int Nb = 1 << logNb, Nc = Nb >> 1, n = Nb * Nb, q = Nc >> 1;
  int tot = n * P;
  GS_FOR(idxAll, tot) {
    int p = idxAll >> (2 * logNb);
    int idx = idxAll & (n - 1);
    int i = idx >> logNb, j = idx & (Nb - 1);
    int ci = (i < q) ? i : ((i >= Nb - q) ? (i - Nb + Nc) : -1);
    int cj = (j < q) ? j : ((j >= Nb - q) ? (j - Nb + Nc) : -1);
    cplx v = make_float2(0.0f, 0.0f);
    if (ci >= 0 && cj >= 0) v = sml[p * Nc * Nc + ci * Nc + cj];
    big[idxAll] = v;
  }
}
// bspec (+)= ph * F_b * him * amask_r;  ph = i^3 = -i ; optionally * lo0 at end
__global__ void accum_band_k(cplx* bspec, const cplx* f, int logN, int b0, int P, int init, int fin) {
  int N = 1 << logN, n = N * N;
  GS_FOR(idx, n) {
    int i = idx >> logN, j = idx & (N - 1);
    float lr, ang;
    grid_lr_ang(i, j, N, &lr, &ang);
    float him = rc_hi_f(lr, -2.0f, -1.0f);
    float ax = 0.0f, ay = 0.0f;
    for (int p = 0; p < P; ++p) {
      float m = him * amask_r(ang, b0 + p);
      cplx z = f[p * n + idx];
      ax += z.y * m;   // -i*(x+iy) = y - i x
      ay -= z.x * m;
    }
    cplx prev = init ? make_float2(0.0f, 0.0f) : bspec[idx];
    prev.x += ax;
    prev.y += ay;
    if (fin) {
      float l0 = rc_lo_f(lr, -1.0f, 0.0f);
      prev.x *= l0;
      prev.y *= l0;
    }
    bspec[idx] = prev;
  }
}
__global__ void add_real_k(float* dst, const cplx* src, int n) {
  GS_FOR(i, n) dst[i] += src[i].x;
}
// gather 9x9 wraparound patch of ifft2(|F|^2)/(N*N); center value -> vari slot
__global__ void ac_gather_k(float* out, const cplx* ac, int N, int base0, int bMul, int stride, double* variAcc) {
  int b = blockIdx.x, t = threadIdx.x;
  if (t >= 81) return;
  int pi = t / 9, pj = t - pi * 9;
  int ii = (pi - 4 + N) & (N - 1);
  int jj = (pj - 4 + N) & (N - 1);
  float v = ac[(size_t)b * N * N + ii * N + jj].x / (float)(N * N);
  out[base0 + b * bMul + t * stride] = v;
  if (variAcc && t == 40 && b == 0) *variAcc = (double)v;
}
__global__ void skewkurt_k(const float* buf, int n, double* s3, double* s4) {
  double a3 = 0, a4 = 0;
  GS_FOR(i, n) {
    double v = (double)buf[i];
    double v2 = v * v;
    a3 += v2 * v;
    a4 += v2 * v2;
  }
  atom_add_wave(s3, a3);
  atom_add_wave(s4, a4);
}
__global__ void img_stats1_k(const float* img, int n, double* sum, float* mm) {
  double s = 0;
  float mn = INFINITY, mx = -INFINITY;
  GS_FOR(i, n) {
    float v = img[i];
    s += (double)v;
    mn = fminf(mn, v);
    mx = fmaxf(mx, v);
  }
  atom_add_wave(sum, s);
#pragma unroll
  for (int o = 32; o > 0; o >>= 1) {
    mn = fminf(mn, __shfl_down(mn, o));
    mx = fmaxf(mx, __shfl_down(mx, o));
  }
  if ((threadIdx.x & 63) == 0) {
    atomicMinF(mm + 0, mn);
    atomicMaxF(mm + 1, mx);
  }
}
__global__ void img_stats2_k(const float* img, int n, const double* sum, double* out3) {
  double mu = *sum / (double)n;
  double s2 = 0, s3 = 0, s4 = 0;
  GS_FOR(i, n) {
    double c = (double)img[i] - mu;
    double c2 = c * c;
    s2 += c2;
    s3 += c2 * c;
    s4 += c2 * c2;
  }
  atom_add_wave(out3 + 0, s2);
  atom_add_wave(out3 + 1, s3);
  atom_add_wave(out3 + 2, s4);
}
// 4x4 gram over 4 contiguous planes (+ optional per-plane sums into slots[16..19])
__global__ void gram4_k(const float* base, int n, double* slots, int withSums) {
  double g[16];
  double s[4];
#pragma unroll
  for (int q = 0; q < 16; ++q) g[q] = 0;
#pragma unroll
  for (int q = 0; q < 4; ++q) s[q] = 0;
  GS_FOR(i, n) {
    double d0 = base[i], d1 = base[n + i], d2 = base[2 * n + i], d3 = base[3 * n + i];
    g[0] += d0 * d0; g[1] += d0 * d1; g[2]  += d0 * d2; g[3]  += d0 * d3;
    g[5] += d1 * d1; g[6] += d1 * d2; g[7]  += d1 * d3;
    g[10] += d2 * d2; g[11] += d2 * d3;
    g[15] += d3 * d3;
    if (withSums) { s[0] += d0; s[1] += d1; s[2] += d2; s[3] += d3; }
  }
  g[4] = g[1]; g[8] = g[2]; g[12] = g[3]; g[9] = g[6]; g[13] = g[7]; g[14] = g[11];
#pragma unroll
  for (int q = 0; q < 16; ++q) atom_add_wave(slots + q, g[q]);
  if (withSums) {
#pragma unroll
    for (int q = 0; q < 4; ++q) atom_add_wave(slots + 16 + q, s[q]);
  }
}
// parent = expanded child band (complex): mg, double-phase real/imag; dots vs 4 mags + 4 realcs
__global__ void parent_reduce_k(const cplx* par, const float* magS, const float* realS, int n, double* slots) {
  double d[13];
#pragma unroll
  for (int q = 0; q < 13; ++q) d[q] = 0;
  GS_FOR(i, n) {
    cplx z = par[i];
    float rt = z.x, it = z.y;
    float mg = sqrtf(rt * rt + it * it);
    float rpr = 0.0f, rpi = 0.0f;
    if (mg > 0.0f) {                 // mg*cos(2*atan2(rt,it)), mg*sin(2*atan2(rt,it))
      rpr = (it * it - rt * rt) / mg;
      rpi = 2.0f * rt * it / mg;
    }
    d[0] += (double)mg;
#pragma unroll
    for (int b = 0; b < 4; ++b) d[1 + b] += (double)magS[b * n + i] * (double)mg;
#pragma unroll
    for (int b = 0; b < 4; ++b) {
      double rv = (double)realS[b * n + i];
      d[5 + b] += rv * (double)rpr;
      d[9 + b] += rv * (double)rpi;
    }
  }
#pragma unroll
  for (int q = 0; q < 13; ++q) atom_add_wave(slots + q, d[q]);
}
// lowpass parents: X and 4 wrap-rolled copies; dots vs realc[3][0..3] (20) + 5x5 gram (25)
__global__ void lp_parent_k(const float* X, const float* realS, int logN, double* slots) {
  int N = 1 << logN, n = N * N;
  double d[45];
#pragma unroll
  for (int q = 0; q < 45; ++q) d[q] = 0;
  GS_FOR(idx, n) {
    int i = idx >> logN, j = idx & (N - 1);
    float c[5];
    c[0] = X[idx];
    c[1] = X[i * N + ((j - 1) & (N - 1))];
    c[2] = X[i * N + ((j + 1) & (N - 1))];
    c[3] = X[((i - 1) & (N - 1)) * N + j];
    c[4] = X[((i + 1) & (N - 1)) * N + j];
#pragma unroll
    for (int b = 0; b < 4; ++b) {
      double rv = (double)realS[b * n + idx];
#pragma unroll
      for (int k = 0; k < 5; ++k) d[b * 5 + k] += rv * (double)c[k];
    }
#pragma unroll
    for (int a = 0; a < 5; ++a)
#pragma unroll
      for (int k = 0; k < 5; ++k) d[20 + a * 5 + k] += (double)c[a] * (double)c[k];
  }
#pragma unroll
  for (int q = 0; q < 45; ++q) atom_add_wave(slots + q, d[q]);
}
__global__ void init_mm_k(float* mm) {
  if (threadIdx.x == 0) { mm[0] = INFINITY; mm[1] = -INFINITY; }
}

// ---------------- final assembly of all scalar stats ----------------
__global__ void assemble_k(float* out, const double* acc, const float* mm) {
  const int t = threadIdx.x;
  const double NPIX = 1048576.0;
  double var0 = acc[1] / (NPIX - 1.0);
  if (t == 0) {
    double mu = acc[0] / NPIX;
    out[0] = (float)mu;
    out[1] = (float)var0;
    out[2] = (float)((acc[2] / NPIX) / pow(var0, 1.5));
    out[3] = (float)((acc[3] / NPIX) / (var0 * var0));
    out[4] = mm[0];
    out[5] = mm[1];
    out[2455] = (float)(acc[4] / NPIX);  // var_hp
  }
  for (int k = t; k < 18; k += blockDim.x) {  // mag_means
    double n;
    if (k == 0) n = NPIX;
    else if (k == 17) n = 4096.0;
    else { int s = (k - 1) >> 2; double dd = (double)(1024 >> s); n = dd * dd; }
    out[6 + k] = (float)(acc[8 + k] / n);
  }
  for (int si = t; si < 5; si += blockDim.x) {  // skew_r / kurt_r
    double dd = (si == 4) ? 64.0 : (double)(1024 >> si);
    double nn = dd * dd;
    double vari = acc[32 + si];
    bool cond = (vari / var0) > 1e-6;
    double m3 = acc[40 + si] / nn, m4 = acc[48 + si] / nn;
    out[1320 + si] = (float)(cond ? m3 / pow(vari, 1.5) : 0.0);
    out[1325 + si] = (float)(cond ? m4 / (vari * vari) : 3.0);
  }
  for (int q = t; q < 64; q += blockDim.x) {  // coc_mag s=0..3
    int s = q >> 4, ij = q & 15;
    double dd = (double)(1024 >> s); double csz = dd * dd;
    out[1735 + ij * 5 + s] = (float)(acc[64 + s * 20 + ij] / csz);
  }
  for (int q = t; q < 64; q += blockDim.x) {  // coc_real s=0..3 (top-left 4x4 of 8x8)
    int s = q >> 4, ij = q & 15;
    int i = ij >> 2, j = ij & 3;
    double dd = (double)(1024 >> s); double csz = dd * dd;
    out[1879 + (i * 8 + j) * 5 + s] = (float)(acc[144 + s * 16 + ij] / csz);
  }
  for (int q = t; q < 25; q += blockDim.x) {  // coc_real s=4 (5x5, /(csz/4))
    int a = q / 5, b2 = q - a * 5;
    out[1879 + (a * 8 + b2) * 5 + 4] = (float)(acc[390 + q] / 4096.0);
  }
  for (int q = t; q < 48; q += blockDim.x) {  // csc_mag s=0..2
    int s = q >> 4, ij = q & 15;
    int i = ij >> 2, pb = ij & 3;
    double dd = (double)(1024 >> s); double csz = dd * dd;
    const double* ps = acc + 208 + (s * 4 + pb) * 13;
    double meanp = ps[0] / csz;
    double cousSum = acc[64 + s * 20 + 16 + i];
    out[1815 + (i * 4 + pb) * 4 + s] = (float)((ps[1 + i] - meanp * cousSum) / csz);
  }
  for (int q = t; q < 96; q += blockDim.x) {  // csc_real s=0..2 (4x8)
    int s = q >> 5, r = q & 31;
    int i = r >> 3, j = r & 7;
    int pb = j & 3, offq = (j >= 4) ? 9 : 5;
    double dd = (double)(1024 >> s); double csz = dd * dd;
    out[2199 + (i * 8 + j) * 4 + s] = (float)(acc[208 + (s * 4 + pb) * 13 + offq + i] / csz);
  }
  for (int q = t; q < 20; q += blockDim.x) {  // csc_real s=3 (4x5)
    int i = q / 5, c = q - i * 5;
    out[2199 + (i * 8 + c) * 4 + 3] = (float)(acc[370 + q] / 16384.0);
  }
}

// ---------------- host-side helpers ----------------
static void fft_rows(cplx* d, int N, int rows, bool inv, hipStream_t st) {
  dim3 g(rows);
  int T = (N >= 512) ? 256 : ((N == 256) ? 128 : 64);
  dim3 b(T);
  switch (N) {
    case 64:   if (inv) fft_rows_k<6,  true><<<g, b, 0, st>>>(d); else fft_rows_k<6,  false><<<g, b, 0, st>>>(d); break;
    case 128:  if (inv) fft_rows_k<7,  true><<<g, b, 0, st>>>(d); else fft_rows_k<7,  false><<<g, b, 0, st>>>(d); break;
    case 256:  if (inv) fft_rows_k<8,  true><<<g, b, 0, st>>>(d); else fft_rows_k<8,  false><<<g, b, 0, st>>>(d); break;
    case 512:  if (inv) fft_rows_k<9,  true><<<g, b, 0, st>>>(d); else fft_rows_k<9,  false><<<g, b, 0, st>>>(d); break;
    case 1024: if (inv) fft_rows_k<10, true><<<g, b, 0, st>>>(d); else fft_rows_k<10, false><<<g, b, 0, st>>>(d); break;
    default: break;
  }
}
static void fft2d(cplx* a, cplx* b, int N, int P, bool inv, hipStream_t st) {
  fft_rows(a, N, N * P, inv, st);
  dim3 tg(N / 32, N / 32, P), tb(32, 8);
  transpose_k<<<tg, tb, 0, st>>>(b, a, N);
  fft_rows(b, N, N * P, inv, st);
  transpose_k<<<tg, tb, 0, st>>>(a, b, N);
}
static inline dim3 gsz(int n) {
  int b = (n + 255) >> 8;
  if (b > 2048) b = 2048;
  if (b < 1) b = 1;
  return dim3(b);
}

extern "C" void kernel_launch(void* const* d_in, const int* in_sizes, int n_in,
                              void* d_out, int out_size, void* d_ws, size_t ws_size,
                              hipStream_t stream) {
  (void)in_sizes; (void)n_in; (void)out_size; (void)ws_size;
  const float* img = (const float*)d_in[0];
  float* out = (float*)d_out;

  char* wsb = (char*)d_ws;
  size_t off = 0;
  auto alloc = [&](size_t bytes) -> void* {
    void* p = wsb + off;
    off += (bytes + 255) & ~(size_t)255;
    return p;
  };
  const size_t MB = (size_t)1 << 20;
  cplx* cA = (cplx*)alloc(8 * MB);
  cplx* cB = (cplx*)alloc(8 * MB);
  cplx* cC = (cplx*)alloc(8 * MB);
  cplx* LOD[5];
  for (int s = 0; s < 5; ++s) {
    int N = 1024 >> s;
    LOD[s] = (cplx*)alloc((size_t)N * N * sizeof(cplx));
  }
  cplx* COEFF[4] = {nullptr, nullptr, nullptr, nullptr};
  for (int s = 1; s <= 3; ++s) {
    int N = 1024 >> s;
    COEFF[s] = (cplx*)alloc((size_t)4 * N * N * sizeof(cplx));
  }
  float* MAG[4];
  float* REALC[4];
  for (int s = 0; s < 4; ++s) {
    int N = 1024 >> s;
    MAG[s] = (float*)alloc((size_t)4 * N * N * sizeof(float));
  }
  for (int s = 0; s < 4; ++s) {
    int N = 1024 >> s;
    REALC[s] = (float*)alloc((size_t)4 * N * N * sizeof(float));
  }
  const int NPIX = 1024 * 1024;
  float* RHP   = (float*)alloc((size_t)NPIX * 4);
  float* RECON = (float*)alloc((size_t)NPIX * 4);
  float* RLP   = (float*)alloc(64 * 64 * 4);
  float* XBUF  = (float*)alloc(128 * 128 * 4);
  double* ACC  = (double*)alloc(512 * 8);
  float* MM    = (float*)alloc(256);

  hipMemsetAsync(out, 0, 2456 * sizeof(float), stream);
  hipMemsetAsync(ACC, 0, 512 * 8, stream);
  init_mm_k<<<1, 64, 0, stream>>>(MM);

  // ---- Phase A: pixel stats ----
  img_stats1_k<<<gsz(NPIX), 256, 0, stream>>>(img, NPIX, ACC + 0, MM);
  img_stats2_k<<<gsz(NPIX), 256, 0, stream>>>(img, NPIX, ACC + 0, ACC + 1);

  // ---- Phase B: steerable pyramid ----
  r2c_k<<<gsz(NPIX), 256, 0, stream>>>(cC, img, NPIX);
  fft2d(cC, cB, 1024, 1, false, stream);
  hp_lo_split_k<<<gsz(NPIX), 256, 0, stream>>>(cA, LOD[0], cC, 10);
  fft2d(cA, cB, 1024, 1, true, stream);
  rhp_extract_k<<<gsz(NPIX), 256, 0, stream>>>(RHP, cA, NPIX, ACC + 8, ACC + 4);
  for (int b = 0; b < 4; ++b) {  // s=0 per-band (8MB planes)
    band_spec_k<<<gsz(NPIX), 256, 0, stream>>>(cA, LOD[0], 10, b, 1);
    fft2d(cA, cB, 1024, 1, true, stream);
    extract_band_k<<<gsz(NPIX), 256, 0, stream>>>(REALC[0] + (size_t)b * NPIX, MAG[0] + (size_t)b * NPIX,
                                                  nullptr, cA, 20, 1, ACC + 9 + b);
    center_k<<<gsz(NPIX), 256, 0, stream>>>(MAG[0] + (size_t)b * NPIX, 20, 1, ACC + 9 + b);
  }
  lod_down_k<<<gsz(512 * 512), 256, 0, stream>>>(LOD[1], LOD[0], 9);
  for (int s = 1; s <= 3; ++s) {  // batched 4 bands
    int N = 1024 >> s, logN = 10 - s, n = N * N;
    band_spec_k<<<gsz(n), 256, 0, stream>>>(cA, LOD[s], logN, 0, 4);
    fft2d(cA, cB, N, 4, true, stream);
    extract_band_k<<<gsz(4 * n), 256, 0, stream>>>(REALC[s], MAG[s], COEFF[s], cA, 2 * logN, 4, ACC + 9 + s * 4);
    center_k<<<gsz(4 * n), 256, 0, stream>>>(MAG[s], 2 * logN, 4, ACC + 9 + s * 4);
    lod_down_k<<<gsz((N / 2) * (N / 2)), 256, 0, stream>>>(LOD[s + 1], LOD[s], logN - 1);
  }
  fft2d(LOD[4], cB, 64, 1, true, stream);  // residual lowpass -> spatial
  extract_real_k<<<gsz(4096), 256, 0, stream>>>(RLP, LOD[4], 4096, ACC + 56);
  center_abs_k<<<gsz(4096), 256, 0, stream>>>(RLP, 4096, ACC + 56, ACC + 8 + 17);

  // ---- Phase C: recon chain, autocorrs, skew/kurt ----
  r2c_k<<<gsz(4096), 256, 0, stream>>>(cA, RLP, 4096);  // recon = lo0_filter(RLP)
  fft2d(cA, cB, 64, 1, false, stream);
  mul_lo0_k<<<gsz(4096), 256, 0, stream>>>(cA, 6);
  fft2d(cA, cB, 64, 1, true, stream);
  extract_real_k<<<gsz(4096), 256, 0, stream>>>(RECON, cA, 4096, nullptr);
  {  // level n_scales (=4)
    r2c_k<<<gsz(4096), 256, 0, stream>>>(cA, RECON, 4096);
    fft2d(cA, cB, 64, 1, false, stream);
    sqmag_k<<<gsz(4096), 256, 0, stream>>>(cA, 4096);
    fft2d(cA, cB, 64, 1, true, stream);
    ac_gather_k<<<1, 96, 0, stream>>>(out, cA, 64, 1330 + 4, 0, 5, ACC + 36);
    skewkurt_k<<<gsz(4096), 256, 0, stream>>>(RECON, 4096, ACC + 44, ACC + 52);
  }
  for (int s = 3; s >= 0; --s) {
    int N = 1024 >> s, logN = 10 - s, n = N * N, half = N >> 1;
    if (s >= 1) {  // acm: autocorr of 4 centered mags (batched)
      r2c_k<<<gsz(4 * n), 256, 0, stream>>>(cA, MAG[s], 4 * n);
      fft2d(cA, cB, N, 4, false, stream);
      sqmag_k<<<gsz(4 * n), 256, 0, stream>>>(cA, 4 * n);
      fft2d(cA, cB, N, 4, true, stream);
      ac_gather_k<<<4, 96, 0, stream>>>(out, cA, N, 24 + s * 4, 1, 16, nullptr);
    } else {
      for (int b = 0; b < 4; ++b) {
        r2c_k<<<gsz(n), 256, 0, stream>>>(cA, MAG[0] + (size_t)b * n, n);
        fft2d(cA, cB, N, 1, false, stream);
        sqmag_k<<<gsz(n), 256, 0, stream>>>(cA, n);
        fft2d(cA, cB, N, 1, true, stream);
        ac_gather_k<<<1, 96, 0, stream>>>(out, cA, N, 24 + b, 0, 16, nullptr);
      }
    }
    // recon = real(ifft2(embed(fft2(recon))))  (expand/4 folded to net scale 1)
    r2c_k<<<gsz(half * half), 256, 0, stream>>>(cA, RECON, half * half);
    fft2d(cA, cB, half, 1, false, stream);
    embed_k<<<gsz(n), 256, 0, stream>>>(cC, cA, logN, 1);
    fft2d(cC, cB, N, 1, true, stream);
    extract_real_k<<<gsz(n), 256, 0, stream>>>(RECON, cC, n, nullptr);
    // recon += recon_band(realc[s][:])
    if (s >= 1) {
      r2c_k<<<gsz(4 * n), 256, 0, stream>>>(cA, REALC[s], 4 * n);
      fft2d(cA, cB, N, 4, false, stream);
      accum_band_k<<<gsz(n), 256, 0, stream>>>(cC, cA, logN, 0, 4, 1, 1);
    } else {
      for (int b = 0; b < 4; ++b) {
        r2c_k<<<gsz(n), 256, 0, stream>>>(cA, REALC[0] + (size_t)b * n, n);
        fft2d(cA, cB, N, 1, false, stream);
        accum_band_k<<<gsz(n), 256, 0, stream>>>(cC, cA, logN, b, 1, (b == 0) ? 1 : 0, (b == 3) ? 1 : 0);
      }
    }
    fft2d(cC, cB, N, 1, true, stream);
    add_real_k<<<gsz(n), 256, 0, stream>>>(RECON, cC, n);
    // autocorr + skew/kurt of recon
    r2c_k<<<gsz(n), 256, 0, stream>>>(cA, RECON, n);
    fft2d(cA, cB, N, 1, false, stream);
    sqmag_k<<<gsz(n), 256, 0, stream>>>(cA, n);
    fft2d(cA, cB, N, 1, true, stream);
    ac_gather_k<<<1, 96, 0, stream>>>(out, cA, N, 1330 + s, 0, 5, ACC + 32 + s);
    skewkurt_k<<<gsz(n), 256, 0, stream>>>(RECON, n, ACC + 40 + s, ACC + 48 + s);
  }

  // ---- Phase D: cross-correlations ----
  for (int s = 0; s < 4; ++s) {
    int N = 1024 >> s, logN = 10 - s, n = N * N;
    gram4_k<<<gsz(n), 256, 0, stream>>>(MAG[s], n, ACC + 64 + s * 20, 1);
    gram4_k<<<gsz(n), 256, 0, stream>>>(REALC[s], n, ACC + 144 + s * 16, 0);
    if (s < 3) {
      int Nc = N >> 1, nc = Nc * Nc;
      if (s == 0) {
        for (int pb = 0; pb < 4; ++pb) {
          hipMemcpyAsync(cA, COEFF[1] + (size_t)pb * nc, (size_t)nc * sizeof(cplx), hipMemcpyDeviceToDevice, stream);
          fft2d(cA, cB, Nc, 1, false, stream);
          embed_k<<<gsz(n), 256, 0, stream>>>(cC, cA, logN, 1);
          fft2d(cC, cB, N, 1, true, stream);
          parent_reduce_k<<<gsz(n), 256, 0, stream>>>(cC, MAG[0], REALC[0], n, ACC + 208 + pb * 13);
        }
      } else {
        hipMemcpyAsync(cA, COEFF[s + 1], (size_t)4 * nc * sizeof(cplx), hipMemcpyDeviceToDevice, stream);
        fft2d(cA, cB, Nc, 4, false, stream);
        embed_k<<<gsz(4 * n), 256, 0, stream>>>(cC, cA, logN, 4);
        fft2d(cC, cB, N, 4, true, stream);
        for (int pb = 0; pb < 4; ++pb)
          parent_reduce_k<<<gsz(n), 256, 0, stream>>>(cC + (size_t)pb * n, MAG[s], REALC[s], n,
                                                      ACC + 208 + (s * 4 + pb) * 13);
      }
    } else {  // s==3: expanded lowpass + 4 rolls
      r2c_k<<<gsz(4096), 256, 0, stream>>>(cA, RLP, 4096);
      fft2d(cA, cB, 64, 1, false, stream);
      embed_k<<<gsz(128 * 128), 256, 0, stream>>>(cC, cA, 7, 1);
      fft2d(cC, cB, 128, 1, true, stream);
      extract_real_k<<<gsz(128 * 128), 256, 0, stream>>>(XBUF, cC, 128 * 128, nullptr);
      lp_parent_k<<<gsz(128 * 128), 256, 0, stream>>>(XBUF, REALC[3], 7, ACC + 370);
    }
  }

  assemble_k<<<1, 256, 0, stream>>>(out, ACC, MM);
}